// Round 8
// baseline (436.679 us; speedup 1.0000x reference)
//
#include <hip/hip_runtime.h>
#include <stdint.h>

// ---------------------------------------------------------------------------
// SPP: out[n] = b + W @ [mean0(b) | mean2(s2) | mean4(s4) | mean8(s8)]
// v8: = v7 + non-temporal streaming hints: NT stores for out (keep sums2
//     L3-resident for the gathers), NT loads for read-once feats/coords/batch.
// ---------------------------------------------------------------------------

#define N_PTS   1048576
#define NB      4
#define N2SEG   (NB*64*64*64)   // 1,048,576
#define N4SEG   (NB*32*32*32)   // 131,072
#define N8SEG   (NB*16*16*16)   // 16,384

typedef unsigned int uint;

// workspace offsets (bytes)
#define OFF_SUMS2  ((size_t)0)            // N2SEG*64 bf16 = 134,217,728
#define OFF_CNT2   ((size_t)134217728)    // N2SEG u32     =   4,194,304
#define OFF_SUMS0F ((size_t)138412032)    // 256 f32 (pad 1024)
#define MEMSET_END ((size_t)138413056)    // zeroed region (16B-multiple)
#define OFF_SUMS4  ((size_t)138413056)    // N4SEG*64 bf16 =  16,777,216
#define OFF_MEAN4  ((size_t)155190272)    // N4SEG*64 bf16 =  16,777,216
#define OFF_CNT4   ((size_t)171967488)    // N4SEG u32     =     524,288
#define OFF_SUMS8  ((size_t)172491776)    // N8SEG*64 bf16 =   2,097,152
#define OFF_MEAN8  ((size_t)174588928)    // N8SEG*64 bf16 =   2,097,152
#define OFF_CNT8   ((size_t)176686080)    // N8SEG u32     =      65,536
#define OFF_MEAN0  ((size_t)176751616)    // 4*32 u32 (pad 1024)
#define OFF_WF     ((size_t)176752640)    // 48 KB frag-ready W
#define WS_NEEDED  ((size_t)176801792)

// dword offsets into workspace (for k_final's single-base addressing)
#define D_S2 0u
#define D_C2 ((uint)(OFF_CNT2 / 4))
#define D_M4 ((uint)(OFF_MEAN4 / 4))
#define D_M8 ((uint)(OFF_MEAN8 / 4))
#define D_M0 ((uint)(OFF_MEAN0 / 4))

typedef short s8v __attribute__((ext_vector_type(8)));   // 8 bf16 (4 VGPR)
typedef float f4v __attribute__((ext_vector_type(4)));   // MFMA C/D
typedef uint  u4v __attribute__((ext_vector_type(4)));   // NT-store-friendly
typedef float f2v __attribute__((ext_vector_type(2)));   // NT-load-friendly

__device__ __forceinline__ uint pack_bf16x2(float a, float b) {
  uint ua = __float_as_uint(a), ub = __float_as_uint(b);
  ua = (ua + 0x7fffu + ((ua >> 16) & 1u)) >> 16;   // RNE
  ub = (ub + 0x7fffu + ((ub >> 16) & 1u)) >> 16;
  return (ub << 16) | ua;
}
__device__ __forceinline__ float bflo(uint u) { return __uint_as_float(u << 16); }
__device__ __forceinline__ float bfhi(uint u) { return __uint_as_float(u & 0xffff0000u); }

__device__ __forceinline__ uint scale_pk(uint u, float rc) {
  return pack_bf16x2(bflo(u) * rc, bfhi(u) * rc);
}

// ---- fast zero of the atomic-accumulated region (16B granularity)
#define ZERO_U4 (MEMSET_END / 16)
__global__ __launch_bounds__(256) void k_zero(u4v* __restrict__ p) {
  u4v z = (u4v)0u;
  size_t stride = (size_t)gridDim.x * 256;
  for (size_t i = blockIdx.x * 256ull + threadIdx.x; i < ZERO_U4; i += stride)
    __builtin_nontemporal_store(z, &p[i]);
}

// ---- frag-ready W: Wf[((kt*6+nt)*64+l)*4+d] = pack(W[n][k], W[n][k+1])
//      n = nt*16+(l&15), k = kt*32+(l>>4)*8+2d   (B[k][n] = W[n][k])
__global__ __launch_bounds__(256) void k_wf(const float* __restrict__ W,
                                            uint* __restrict__ Wf) {
  int idx = blockIdx.x * 256 + threadIdx.x;        // < 12288
  int d = idx & 3, l = (idx >> 2) & 63, ktnt = idx >> 8;
  int kt = ktnt / 6, nt = ktnt - kt * 6;
  int n = nt * 16 + (l & 15);
  int k = kt * 32 + (l >> 4) * 8 + d * 2;
  Wf[idx] = pack_bf16x2(W[n * 256 + k], W[n * 256 + k + 1]);
}

// ---- scatter: 2 points per wave, lane = (half, channel-pair), pk-bf16 atomics
//      NT loads on the read-once streams keep L2/L3 for the atomic targets.
__global__ __launch_bounds__(256) void k_scatter2(
    const float* __restrict__ feats, const int* __restrict__ coords,
    const int* __restrict__ batch, uint* __restrict__ sums2,
    uint* __restrict__ cnt2)
{
  int l = threadIdx.x & 63;
  int c2 = l & 31, half = l >> 5;
  int wid = (blockIdx.x * 256 + threadIdx.x) >> 6;
  int nw = (gridDim.x * 256) >> 6;
  for (int p0 = wid * 2; p0 < N_PTS; p0 += nw * 2) {
    int p = p0 + half;
    f2v f = __builtin_nontemporal_load(((const f2v*)feats) + (size_t)p * 32 + c2);
    int b = __builtin_nontemporal_load(&batch[p]);
    int x = __builtin_nontemporal_load(&coords[3 * p]);
    int y = __builtin_nontemporal_load(&coords[3 * p + 1]);
    int z = __builtin_nontemporal_load(&coords[3 * p + 2]);
    int s2 = ((b * 64 + (x >> 1)) * 64 + (y >> 1)) * 64 + (z >> 1);
    uint pk = pack_bf16x2(f.x, f.y);
    uint64_t addr = (uint64_t)(uintptr_t)(sums2 + (size_t)s2 * 32 + c2);
    asm volatile("global_atomic_pk_add_bf16 %0, %1, off"
                 :: "v"(addr), "v"(pk));
    if (c2 == 0) atomicAdd(&cnt2[s2], 1u);
  }
}

// ---- 8-child tree reduction; writes raw sums (next level), pre-scaled mean,
//      and cnt. thread = (sc, c2)
__global__ __launch_bounds__(256) void k_down_bf(
    const uint* __restrict__ sumsF, const uint* __restrict__ cntF,
    uint* __restrict__ sumsC, uint* __restrict__ meanC,
    uint* __restrict__ cntC, int lgC, int nC)
{
  int tid = blockIdx.x * 256 + threadIdx.x;
  int sc = tid >> 5, c2 = tid & 31;
  if (sc >= nC) return;
  int CG = 1 << lgC, FG = CG << 1;
  int b = sc >> (3 * lgC);
  int r = sc & ((1 << (3 * lgC)) - 1);
  int x = r >> (2 * lgC), y = (r >> lgC) & (CG - 1), z = r & (CG - 1);
  float sx = 0.f, sy = 0.f;
  uint cn = 0;
  #pragma unroll
  for (int dx = 0; dx < 2; ++dx)
    #pragma unroll
    for (int dy = 0; dy < 2; ++dy)
      #pragma unroll
      for (int dz = 0; dz < 2; ++dz) {
        int sf = ((b * FG + 2 * x + dx) * FG + (2 * y + dy)) * FG + (2 * z + dz);
        uint u = sumsF[(size_t)sf * 32 + c2];
        sx += bflo(u); sy += bfhi(u);
        cn += cntF[sf];                       // same addr across 32 lanes: L1 broadcast
      }
  sumsC[(size_t)sc * 32 + c2] = pack_bf16x2(sx, sy);
  float rc = 1.0f / (float)(cn > 1u ? cn : 1u);
  meanC[(size_t)sc * 32 + c2] = pack_bf16x2(sx * rc, sy * rc);
  if (c2 == 0) cntC[sc] = cn;
}

// ---- per-batch global partial reduce (32 blocks/batch), f32 atomics
__global__ __launch_bounds__(256) void k_gpart(
    const uint* __restrict__ sums8, float* __restrict__ sums0f)
{
  __shared__ float2 red[8][32];
  int b = blockIdx.x >> 5, chunk = blockIdx.x & 31;
  int t = threadIdx.x, c2 = t & 31, g = t >> 5;
  float sx = 0.f, sy = 0.f;
  for (int i = g; i < 128; i += 8) {
    uint u = sums8[(size_t)(b * 4096 + chunk * 128 + i) * 32 + c2];
    sx += bflo(u); sy += bfhi(u);
  }
  red[g][c2] = make_float2(sx, sy);
  __syncthreads();
  if (g == 0) {
    float ax = 0.f, ay = 0.f;
    #pragma unroll
    for (int i = 0; i < 8; ++i) { ax += red[i][c2].x; ay += red[i][c2].y; }
    unsafeAtomicAdd(&sums0f[b * 64 + 2 * c2], ax);
    unsafeAtomicAdd(&sums0f[b * 64 + 2 * c2 + 1], ay);
  }
}

// ---- finalize level 0: cnt0 from cnt8, mean0 = sums0f/cnt0 (bf16, pre-scaled)
__global__ __launch_bounds__(256) void k_fin0(
    const float* __restrict__ sums0f, const uint* __restrict__ cnt8,
    uint* __restrict__ mean0)
{
  __shared__ uint redc[256];
  __shared__ float rcs[NB];
  int t = threadIdx.x;
  uint cn = 0;
  for (int i = 0; i < 64; ++i) cn += cnt8[t * 64 + i];
  redc[t] = cn;
  __syncthreads();
  if (t < NB) {
    uint s = 0;
    for (int i = 0; i < 64; ++i) s += redc[t * 64 + i];
    rcs[t] = 1.0f / (float)(s > 1u ? s : 1u);
  }
  __syncthreads();
  if (t < 128) {
    int b = t >> 5, c2 = t & 31;
    float rc = rcs[b];
    mean0[b * 32 + c2] =
        pack_bf16x2(sums0f[b * 64 + 2 * c2] * rc, sums0f[b * 64 + 2 * c2 + 1] * rc);
  }
}

// ---- fused gather-GEMM, depth-2 pipelined; NT stores for the out stream
//      (no-allocate keeps sums2/mean4 L3-resident for the gathers).
#define GPB 8
__global__ __launch_bounds__(256) void k_final(
    const int* __restrict__ coords, const int* __restrict__ batch,
    const uint* __restrict__ wsb,     // workspace base, dword-indexed
    const uint4* __restrict__ Wf, const float* __restrict__ bias,
    float* __restrict__ out)
{
  __shared__ uint4 wf[3072];   // 48 KB frag-ready W
  int t = threadIdx.x;
  #pragma unroll
  for (int i = 0; i < 12; ++i) wf[i * 256 + t] = Wf[i * 256 + t];
  int l = t & 63, w = t >> 6, pl = l & 15, q = l >> 4;
  float bn[6];
  #pragma unroll
  for (int nt = 0; nt < 6; ++nt) bn[nt] = bias[nt * 16 + pl];
  __syncthreads();

  uint4 afc[8];   // current iteration's A fragments
  uint cvc;       // current cnt2
  {
    int p = blockIdx.x * (GPB * 64) + w * 16 + pl;   // g = 0
    int b = __builtin_nontemporal_load(&batch[p]);
    int x = __builtin_nontemporal_load(&coords[3 * p]);
    int y = __builtin_nontemporal_load(&coords[3 * p + 1]);
    int z = __builtin_nontemporal_load(&coords[3 * p + 2]);
    int s2 = ((b * 64 + (x >> 1)) * 64 + (y >> 1)) * 64 + (z >> 1);
    int s4 = ((b * 32 + (x >> 2)) * 32 + (y >> 2)) * 32 + (z >> 2);
    int s8 = ((b * 16 + (x >> 3)) * 16 + (y >> 3)) * 16 + (z >> 3);
    const uint4* a0 = (const uint4*)(wsb + D_M0 + b * 32);
    const uint4* a2 = (const uint4*)(wsb + D_S2 + s2 * 32);
    const uint4* a4 = (const uint4*)(wsb + D_M4 + s4 * 32);
    const uint4* a8 = (const uint4*)(wsb + D_M8 + s8 * 32);
    afc[0] = a0[q];     afc[1] = a0[4 + q];
    afc[2] = a2[q];     afc[3] = a2[4 + q];
    afc[4] = a4[q];     afc[5] = a4[4 + q];
    afc[6] = a8[q];     afc[7] = a8[4 + q];
    cvc = wsb[D_C2 + s2];
  }

  #pragma unroll 1
  for (int g = 0; g < GPB; ++g) {
    uint4 afn[8];
    uint cvn = 0;
    if (g + 1 < GPB) {   // issue next iteration's gathers first
      int p = blockIdx.x * (GPB * 64) + (g + 1) * 64 + w * 16 + pl;
      int b = __builtin_nontemporal_load(&batch[p]);
      int x = __builtin_nontemporal_load(&coords[3 * p]);
      int y = __builtin_nontemporal_load(&coords[3 * p + 1]);
      int z = __builtin_nontemporal_load(&coords[3 * p + 2]);
      int s2 = ((b * 64 + (x >> 1)) * 64 + (y >> 1)) * 64 + (z >> 1);
      int s4 = ((b * 32 + (x >> 2)) * 32 + (y >> 2)) * 32 + (z >> 2);
      int s8 = ((b * 16 + (x >> 3)) * 16 + (y >> 3)) * 16 + (z >> 3);
      const uint4* a0 = (const uint4*)(wsb + D_M0 + b * 32);
      const uint4* a2 = (const uint4*)(wsb + D_S2 + s2 * 32);
      const uint4* a4 = (const uint4*)(wsb + D_M4 + s4 * 32);
      const uint4* a8 = (const uint4*)(wsb + D_M8 + s8 * 32);
      afn[0] = a0[q];     afn[1] = a0[4 + q];
      afn[2] = a2[q];     afn[3] = a2[4 + q];
      afn[4] = a4[q];     afn[5] = a4[4 + q];
      afn[6] = a8[q];     afn[7] = a8[4 + q];
      cvn = wsb[D_C2 + s2];
    }

    // process current
    float rc = 1.0f / (float)(cvc > 1u ? cvc : 1u);
    afc[2].x = scale_pk(afc[2].x, rc); afc[2].y = scale_pk(afc[2].y, rc);
    afc[2].z = scale_pk(afc[2].z, rc); afc[2].w = scale_pk(afc[2].w, rc);
    afc[3].x = scale_pk(afc[3].x, rc); afc[3].y = scale_pk(afc[3].y, rc);
    afc[3].z = scale_pk(afc[3].z, rc); afc[3].w = scale_pk(afc[3].w, rc);
    f4v acc[6];
    #pragma unroll
    for (int nt = 0; nt < 6; ++nt) acc[nt] = (f4v)0.0f;
    #pragma unroll
    for (int kt = 0; kt < 8; ++kt) {
      s8v afr = __builtin_bit_cast(s8v, afc[kt]);
      #pragma unroll
      for (int nt = 0; nt < 6; ++nt) {
        s8v bf = __builtin_bit_cast(s8v, wf[(kt * 6 + nt) * 64 + l]);
        acc[nt] = __builtin_amdgcn_mfma_f32_16x16x32_bf16(afr, bf, acc[nt], 0, 0, 0);
      }
    }
    // D layout: row m = q*4+r (point pbase+m), col = pl (channel nt*16+pl)
    int pbase = blockIdx.x * (GPB * 64) + g * 64 + w * 16;
    float* ob = out + (size_t)(pbase + q * 4) * 96 + pl;
    #pragma unroll
    for (int nt = 0; nt < 6; ++nt)
      #pragma unroll
      for (int r = 0; r < 4; ++r)
        __builtin_nontemporal_store(bn[nt] + acc[nt][r], &ob[r * 96 + nt * 16]);

    // rotate pipeline
    #pragma unroll
    for (int i = 0; i < 8; ++i) afc[i] = afn[i];
    cvc = cvn;
  }
}

extern "C" void kernel_launch(void* const* d_in, const int* in_sizes, int n_in,
                              void* d_out, int out_size, void* d_ws, size_t ws_size,
                              hipStream_t stream)
{
  const float* feats  = (const float*)d_in[0];
  const int*   coords = (const int*)d_in[1];
  const int*   batch  = (const int*)d_in[2];
  const float* W      = (const float*)d_in[3];
  const float* bias   = (const float*)d_in[4];
  float* out = (float*)d_out;
  char* ws = (char*)d_ws;
  if (ws_size < WS_NEEDED) return;

  uint*  sums2  = (uint*)(ws + OFF_SUMS2);
  uint*  cnt2   = (uint*)(ws + OFF_CNT2);
  float* sums0f = (float*)(ws + OFF_SUMS0F);
  uint*  sums4  = (uint*)(ws + OFF_SUMS4);
  uint*  mean4  = (uint*)(ws + OFF_MEAN4);
  uint*  cnt4   = (uint*)(ws + OFF_CNT4);
  uint*  sums8  = (uint*)(ws + OFF_SUMS8);
  uint*  mean8  = (uint*)(ws + OFF_MEAN8);
  uint*  cnt8   = (uint*)(ws + OFF_CNT8);
  uint*  mean0  = (uint*)(ws + OFF_MEAN0);
  uint*  Wf     = (uint*)(ws + OFF_WF);

  k_zero<<<2048, 256, 0, stream>>>((u4v*)ws);
  k_wf<<<48, 256, 0, stream>>>(W, Wf);
  k_scatter2<<<8192, 256, 0, stream>>>(feats, coords, batch, sums2, cnt2);
  k_down_bf<<<(N4SEG * 32) / 256, 256, 0, stream>>>(sums2, cnt2, sums4, mean4, cnt4, 5, N4SEG);
  k_down_bf<<<(N8SEG * 32) / 256, 256, 0, stream>>>(sums4, cnt4, sums8, mean8, cnt8, 4, N8SEG);
  k_gpart<<<128, 256, 0, stream>>>(sums8, sums0f);
  k_fin0<<<1, 256, 0, stream>>>(sums0f, cnt8, mean0);
  k_final<<<N_PTS / (GPB * 64), 256, 0, stream>>>(
      coords, batch, (const uint*)ws, (const uint4*)Wf, bias, out);
}

// Round 9
// 419.029 us; speedup vs baseline: 1.0421x; 1.0421x over previous
//
#include <hip/hip_runtime.h>
#include <stdint.h>

// ---------------------------------------------------------------------------
// SPP: out[n] = b + W @ [mean0(b) | mean2(s2) | mean4(s4) | mean8(s8)]
// v9: count-first scatter (lambda=1 -> 58% solo voxels use plain stores, not
//     atomics; only multi-rows zero-initialized; sums2 memset eliminated via
//     cnt-guarded down-pass). k_final = v7 exact (best measured).
// ---------------------------------------------------------------------------

#define N_PTS   1048576
#define NB      4
#define N2SEG   (NB*64*64*64)   // 1,048,576
#define N4SEG   (NB*32*32*32)   // 131,072
#define N8SEG   (NB*16*16*16)   // 16,384

typedef unsigned int uint;

// workspace offsets (bytes)
#define OFF_SUMS2  ((size_t)0)            // N2SEG*64 bf16 = 134,217,728 (NOT pre-zeroed)
#define OFF_CNT2   ((size_t)134217728)    // N2SEG u32     =   4,194,304 (zeroed)
#define OFF_SUMS0F ((size_t)138412032)    // 256 f32 (pad 1024, zeroed; contiguous w/ cnt2)
#define ZERO_BEG   OFF_CNT2
#define ZERO_END   ((size_t)138413056)
#define OFF_SUMS4  ((size_t)138413056)    // N4SEG*64 bf16 =  16,777,216
#define OFF_MEAN4  ((size_t)155190272)    // N4SEG*64 bf16 =  16,777,216
#define OFF_CNT4   ((size_t)171967488)    // N4SEG u32     =     524,288
#define OFF_SUMS8  ((size_t)172491776)    // N8SEG*64 bf16 =   2,097,152
#define OFF_MEAN8  ((size_t)174588928)    // N8SEG*64 bf16 =   2,097,152
#define OFF_CNT8   ((size_t)176686080)    // N8SEG u32     =      65,536
#define OFF_MEAN0  ((size_t)176751616)    // 4*32 u32 (pad 1024)
#define OFF_WF     ((size_t)176752640)    // 48 KB frag-ready W
#define WS_NEEDED  ((size_t)176801792)

// dword offsets into workspace (for k_final's single-base addressing)
#define D_S2 0u
#define D_C2 ((uint)(OFF_CNT2 / 4))
#define D_M4 ((uint)(OFF_MEAN4 / 4))
#define D_M8 ((uint)(OFF_MEAN8 / 4))
#define D_M0 ((uint)(OFF_MEAN0 / 4))

typedef short s8v __attribute__((ext_vector_type(8)));   // 8 bf16 (4 VGPR)
typedef float f4v __attribute__((ext_vector_type(4)));   // MFMA C/D
typedef uint  u4v __attribute__((ext_vector_type(4)));
typedef float f2v __attribute__((ext_vector_type(2)));

__device__ __forceinline__ uint pack_bf16x2(float a, float b) {
  uint ua = __float_as_uint(a), ub = __float_as_uint(b);
  ua = (ua + 0x7fffu + ((ua >> 16) & 1u)) >> 16;   // RNE
  ub = (ub + 0x7fffu + ((ub >> 16) & 1u)) >> 16;
  return (ub << 16) | ua;
}
__device__ __forceinline__ float bflo(uint u) { return __uint_as_float(u << 16); }
__device__ __forceinline__ float bfhi(uint u) { return __uint_as_float(u & 0xffff0000u); }

__device__ __forceinline__ uint scale_pk(uint u, float rc) {
  return pack_bf16x2(bflo(u) * rc, bfhi(u) * rc);
}

// ---- zero cnt2 + sums0f (contiguous, 4,195,328 B = 262,208 x 16B)
#define ZCNT_U4 ((ZERO_END - ZERO_BEG) / 16)
__global__ __launch_bounds__(256) void k_zero_cnt(u4v* __restrict__ p) {
  u4v z = (u4v)0u;
  size_t stride = (size_t)gridDim.x * 256;
  for (size_t i = blockIdx.x * 256ull + threadIdx.x; i < ZCNT_U4; i += stride)
    __builtin_nontemporal_store(z, &p[i]);
}

// ---- phase 1: count points per level-2 voxel (1 thread = 1 point)
__global__ __launch_bounds__(256) void k_cnt(
    const int* __restrict__ coords, const int* __restrict__ batch,
    uint* __restrict__ cnt2)
{
  int p = blockIdx.x * 256 + threadIdx.x;          // grid sized exactly N_PTS
  int b = batch[p];
  int x = coords[3 * p], y = coords[3 * p + 1], z = coords[3 * p + 2];
  int s2 = ((b * 64 + (x >> 1)) * 64 + (y >> 1)) * 64 + (z >> 1);
  atomicAdd(&cnt2[s2], 1u);
}

// ---- phase 1.5: zero only rows that will be atomically accumulated (cnt>=2)
//      8 threads per segment, 1 uint4 each (row = 128 B)
__global__ __launch_bounds__(256) void k_zmulti(
    const uint* __restrict__ cnt2, u4v* __restrict__ sums2q)
{
  int tid = blockIdx.x * 256 + threadIdx.x;        // grid = N2SEG*8 exactly
  int seg = tid >> 3, part = tid & 7;
  if (cnt2[seg] >= 2u) sums2q[seg * 8 + part] = (u4v)0u;
}

// ---- frag-ready W: Wf[((kt*6+nt)*64+l)*4+d] = pack(W[n][k], W[n][k+1])
//      n = nt*16+(l&15), k = kt*32+(l>>4)*8+2d   (B[k][n] = W[n][k])
__global__ __launch_bounds__(256) void k_wf(const float* __restrict__ W,
                                            uint* __restrict__ Wf) {
  int idx = blockIdx.x * 256 + threadIdx.x;        // < 12288
  int d = idx & 3, l = (idx >> 2) & 63, ktnt = idx >> 8;
  int kt = ktnt / 6, nt = ktnt - kt * 6;
  int n = nt * 16 + (l & 15);
  int k = kt * 32 + (l >> 4) * 8 + d * 2;
  Wf[idx] = pack_bf16x2(W[n * 256 + k], W[n * 256 + k + 1]);
}

// ---- phase 2: scatter feats. cnt==1 -> plain coalesced store (bit-identical
//      to atomic-into-zero); cnt>=2 -> pk-bf16 atomic into zeroed row.
__global__ __launch_bounds__(256) void k_scatter2(
    const float* __restrict__ feats, const int* __restrict__ coords,
    const int* __restrict__ batch, uint* __restrict__ sums2,
    const uint* __restrict__ cnt2)
{
  int l = threadIdx.x & 63;
  int c2 = l & 31, half = l >> 5;
  int wid = (blockIdx.x * 256 + threadIdx.x) >> 6;
  int nw = (gridDim.x * 256) >> 6;
  for (int p0 = wid * 2; p0 < N_PTS; p0 += nw * 2) {
    int p = p0 + half;
    f2v f = __builtin_nontemporal_load(((const f2v*)feats) + (size_t)p * 32 + c2);
    int b = batch[p];
    int x = coords[3 * p], y = coords[3 * p + 1], z = coords[3 * p + 2];
    int s2 = ((b * 64 + (x >> 1)) * 64 + (y >> 1)) * 64 + (z >> 1);
    uint pk = pack_bf16x2(f.x, f.y);
    uint cv = cnt2[s2];                   // same addr across 32 lanes: broadcast
    uint* dst = sums2 + (size_t)s2 * 32 + c2;
    if (cv == 1u) {
      *dst = pk;                          // solo voxel: no RMW needed
    } else {
      uint64_t addr = (uint64_t)(uintptr_t)dst;
      asm volatile("global_atomic_pk_add_bf16 %0, %1, off"
                   :: "v"(addr), "v"(pk));
    }
  }
}

// ---- 8-child tree reduction; cnt-guarded (empty level-2 rows are unwritten
//      poison -> must skip). Writes raw sums, pre-scaled mean, and cnt.
__global__ __launch_bounds__(256) void k_down_bf(
    const uint* __restrict__ sumsF, const uint* __restrict__ cntF,
    uint* __restrict__ sumsC, uint* __restrict__ meanC,
    uint* __restrict__ cntC, int lgC, int nC)
{
  int tid = blockIdx.x * 256 + threadIdx.x;
  int sc = tid >> 5, c2 = tid & 31;
  if (sc >= nC) return;
  int CG = 1 << lgC, FG = CG << 1;
  int b = sc >> (3 * lgC);
  int r = sc & ((1 << (3 * lgC)) - 1);
  int x = r >> (2 * lgC), y = (r >> lgC) & (CG - 1), z = r & (CG - 1);
  float sx = 0.f, sy = 0.f;
  uint cn = 0;
  #pragma unroll
  for (int dx = 0; dx < 2; ++dx)
    #pragma unroll
    for (int dy = 0; dy < 2; ++dy)
      #pragma unroll
      for (int dz = 0; dz < 2; ++dz) {
        int sf = ((b * FG + 2 * x + dx) * FG + (2 * y + dy)) * FG + (2 * z + dz);
        uint cf = cntF[sf];               // same addr across 32 lanes: broadcast
        if (cf) {
          uint u = sumsF[(size_t)sf * 32 + c2];
          sx += bflo(u); sy += bfhi(u);
        }
        cn += cf;
      }
  sumsC[(size_t)sc * 32 + c2] = pack_bf16x2(sx, sy);
  float rc = 1.0f / (float)(cn > 1u ? cn : 1u);
  meanC[(size_t)sc * 32 + c2] = pack_bf16x2(sx * rc, sy * rc);
  if (c2 == 0) cntC[sc] = cn;
}

// ---- per-batch global partial reduce (32 blocks/batch), f32 atomics
__global__ __launch_bounds__(256) void k_gpart(
    const uint* __restrict__ sums8, float* __restrict__ sums0f)
{
  __shared__ float2 red[8][32];
  int b = blockIdx.x >> 5, chunk = blockIdx.x & 31;
  int t = threadIdx.x, c2 = t & 31, g = t >> 5;
  float sx = 0.f, sy = 0.f;
  for (int i = g; i < 128; i += 8) {
    uint u = sums8[(size_t)(b * 4096 + chunk * 128 + i) * 32 + c2];
    sx += bflo(u); sy += bfhi(u);
  }
  red[g][c2] = make_float2(sx, sy);
  __syncthreads();
  if (g == 0) {
    float ax = 0.f, ay = 0.f;
    #pragma unroll
    for (int i = 0; i < 8; ++i) { ax += red[i][c2].x; ay += red[i][c2].y; }
    unsafeAtomicAdd(&sums0f[b * 64 + 2 * c2], ax);
    unsafeAtomicAdd(&sums0f[b * 64 + 2 * c2 + 1], ay);
  }
}

// ---- finalize level 0: cnt0 from cnt8, mean0 = sums0f/cnt0 (bf16, pre-scaled)
__global__ __launch_bounds__(256) void k_fin0(
    const float* __restrict__ sums0f, const uint* __restrict__ cnt8,
    uint* __restrict__ mean0)
{
  __shared__ uint redc[256];
  __shared__ float rcs[NB];
  int t = threadIdx.x;
  uint cn = 0;
  for (int i = 0; i < 64; ++i) cn += cnt8[t * 64 + i];
  redc[t] = cn;
  __syncthreads();
  if (t < NB) {
    uint s = 0;
    for (int i = 0; i < 64; ++i) s += redc[t * 64 + i];
    rcs[t] = 1.0f / (float)(s > 1u ? s : 1u);
  }
  __syncthreads();
  if (t < 128) {
    int b = t >> 5, c2 = t & 31;
    float rc = rcs[b];
    mean0[b * 32 + c2] =
        pack_bf16x2(sums0f[b * 64 + 2 * c2] * rc, sums0f[b * 64 + 2 * c2 + 1] * rc);
  }
}

// ---- fused gather-GEMM, depth-2 pipelined (v7 exact — best measured)
#define GPB 8
__global__ __launch_bounds__(256) void k_final(
    const int* __restrict__ coords, const int* __restrict__ batch,
    const uint* __restrict__ wsb,     // workspace base, dword-indexed
    const uint4* __restrict__ Wf, const float* __restrict__ bias,
    float* __restrict__ out)
{
  __shared__ uint4 wf[3072];   // 48 KB frag-ready W
  int t = threadIdx.x;
  #pragma unroll
  for (int i = 0; i < 12; ++i) wf[i * 256 + t] = Wf[i * 256 + t];
  int l = t & 63, w = t >> 6, pl = l & 15, q = l >> 4;
  float bn[6];
  #pragma unroll
  for (int nt = 0; nt < 6; ++nt) bn[nt] = bias[nt * 16 + pl];
  __syncthreads();

  uint4 afc[8];   // current iteration's A fragments
  uint cvc;       // current cnt2
  {
    int p = blockIdx.x * (GPB * 64) + w * 16 + pl;   // g = 0
    int b = batch[p];
    int x = coords[3 * p], y = coords[3 * p + 1], z = coords[3 * p + 2];
    int s2 = ((b * 64 + (x >> 1)) * 64 + (y >> 1)) * 64 + (z >> 1);
    int s4 = ((b * 32 + (x >> 2)) * 32 + (y >> 2)) * 32 + (z >> 2);
    int s8 = ((b * 16 + (x >> 3)) * 16 + (y >> 3)) * 16 + (z >> 3);
    const uint4* a0 = (const uint4*)(wsb + D_M0 + b * 32);
    const uint4* a2 = (const uint4*)(wsb + D_S2 + s2 * 32);
    const uint4* a4 = (const uint4*)(wsb + D_M4 + s4 * 32);
    const uint4* a8 = (const uint4*)(wsb + D_M8 + s8 * 32);
    afc[0] = a0[q];     afc[1] = a0[4 + q];
    afc[2] = a2[q];     afc[3] = a2[4 + q];
    afc[4] = a4[q];     afc[5] = a4[4 + q];
    afc[6] = a8[q];     afc[7] = a8[4 + q];
    cvc = wsb[D_C2 + s2];
  }

  #pragma unroll 1
  for (int g = 0; g < GPB; ++g) {
    uint4 afn[8];
    uint cvn = 0;
    if (g + 1 < GPB) {   // issue next iteration's gathers first
      int p = blockIdx.x * (GPB * 64) + (g + 1) * 64 + w * 16 + pl;
      int b = batch[p];
      int x = coords[3 * p], y = coords[3 * p + 1], z = coords[3 * p + 2];
      int s2 = ((b * 64 + (x >> 1)) * 64 + (y >> 1)) * 64 + (z >> 1);
      int s4 = ((b * 32 + (x >> 2)) * 32 + (y >> 2)) * 32 + (z >> 2);
      int s8 = ((b * 16 + (x >> 3)) * 16 + (y >> 3)) * 16 + (z >> 3);
      const uint4* a0 = (const uint4*)(wsb + D_M0 + b * 32);
      const uint4* a2 = (const uint4*)(wsb + D_S2 + s2 * 32);
      const uint4* a4 = (const uint4*)(wsb + D_M4 + s4 * 32);
      const uint4* a8 = (const uint4*)(wsb + D_M8 + s8 * 32);
      afn[0] = a0[q];     afn[1] = a0[4 + q];
      afn[2] = a2[q];     afn[3] = a2[4 + q];
      afn[4] = a4[q];     afn[5] = a4[4 + q];
      afn[6] = a8[q];     afn[7] = a8[4 + q];
      cvn = wsb[D_C2 + s2];
    }

    // process current
    float rc = 1.0f / (float)(cvc > 1u ? cvc : 1u);
    afc[2].x = scale_pk(afc[2].x, rc); afc[2].y = scale_pk(afc[2].y, rc);
    afc[2].z = scale_pk(afc[2].z, rc); afc[2].w = scale_pk(afc[2].w, rc);
    afc[3].x = scale_pk(afc[3].x, rc); afc[3].y = scale_pk(afc[3].y, rc);
    afc[3].z = scale_pk(afc[3].z, rc); afc[3].w = scale_pk(afc[3].w, rc);
    f4v acc[6];
    #pragma unroll
    for (int nt = 0; nt < 6; ++nt) acc[nt] = (f4v)0.0f;
    #pragma unroll
    for (int kt = 0; kt < 8; ++kt) {
      s8v afr = __builtin_bit_cast(s8v, afc[kt]);
      #pragma unroll
      for (int nt = 0; nt < 6; ++nt) {
        s8v bf = __builtin_bit_cast(s8v, wf[(kt * 6 + nt) * 64 + l]);
        acc[nt] = __builtin_amdgcn_mfma_f32_16x16x32_bf16(afr, bf, acc[nt], 0, 0, 0);
      }
    }
    // D layout: row m = q*4+r (point pbase+m), col = pl (channel nt*16+pl)
    int pbase = blockIdx.x * (GPB * 64) + g * 64 + w * 16;
    float* ob = out + (size_t)(pbase + q * 4) * 96 + pl;
    #pragma unroll
    for (int nt = 0; nt < 6; ++nt)
      #pragma unroll
      for (int r = 0; r < 4; ++r)
        ob[r * 96 + nt * 16] = bn[nt] + acc[nt][r];

    // rotate pipeline
    #pragma unroll
    for (int i = 0; i < 8; ++i) afc[i] = afn[i];
    cvc = cvn;
  }
}

extern "C" void kernel_launch(void* const* d_in, const int* in_sizes, int n_in,
                              void* d_out, int out_size, void* d_ws, size_t ws_size,
                              hipStream_t stream)
{
  const float* feats  = (const float*)d_in[0];
  const int*   coords = (const int*)d_in[1];
  const int*   batch  = (const int*)d_in[2];
  const float* W      = (const float*)d_in[3];
  const float* bias   = (const float*)d_in[4];
  float* out = (float*)d_out;
  char* ws = (char*)d_ws;
  if (ws_size < WS_NEEDED) return;

  uint*  sums2  = (uint*)(ws + OFF_SUMS2);
  uint*  cnt2   = (uint*)(ws + OFF_CNT2);
  float* sums0f = (float*)(ws + OFF_SUMS0F);
  uint*  sums4  = (uint*)(ws + OFF_SUMS4);
  uint*  mean4  = (uint*)(ws + OFF_MEAN4);
  uint*  cnt4   = (uint*)(ws + OFF_CNT4);
  uint*  sums8  = (uint*)(ws + OFF_SUMS8);
  uint*  mean8  = (uint*)(ws + OFF_MEAN8);
  uint*  cnt8   = (uint*)(ws + OFF_CNT8);
  uint*  mean0  = (uint*)(ws + OFF_MEAN0);
  uint*  Wf     = (uint*)(ws + OFF_WF);

  k_wf<<<48, 256, 0, stream>>>(W, Wf);
  k_zero_cnt<<<1024, 256, 0, stream>>>((u4v*)(ws + ZERO_BEG));
  k_cnt<<<N_PTS / 256, 256, 0, stream>>>(coords, batch, cnt2);
  k_zmulti<<<(N2SEG * 8) / 256, 256, 0, stream>>>(cnt2, (u4v*)sums2);
  k_scatter2<<<8192, 256, 0, stream>>>(feats, coords, batch, sums2, cnt2);
  k_down_bf<<<(N4SEG * 32) / 256, 256, 0, stream>>>(sums2, cnt2, sums4, mean4, cnt4, 5, N4SEG);
  k_down_bf<<<(N8SEG * 32) / 256, 256, 0, stream>>>(sums4, cnt4, sums8, mean8, cnt8, 4, N8SEG);
  k_gpart<<<128, 256, 0, stream>>>(sums8, sums0f);
  k_fin0<<<1, 256, 0, stream>>>(sums0f, cnt8, mean0);
  k_final<<<N_PTS / (GPB * 64), 256, 0, stream>>>(
      coords, batch, (const uint*)ws, (const uint4*)Wf, bias, out);
}

// Round 10
// 411.455 us; speedup vs baseline: 1.0613x; 1.0184x over previous
//
#include <hip/hip_runtime.h>
#include <stdint.h>

// ---------------------------------------------------------------------------
// SPP: out[n] = b + W @ [mean0(b) | mean2(s2) | mean4(s4) | mean8(s8)]
// v10: = v9 with k_final restructured: per-block index prologue into LDS
//      (s2 + packed s4/s8, 4KB) + depth-3 gather pipeline with named buffers
//      (hand-unrolled ISSUE/CONSUME schedule). Target VGPR <= 168.
// ---------------------------------------------------------------------------

#define N_PTS   1048576
#define NB      4
#define N2SEG   (NB*64*64*64)   // 1,048,576
#define N4SEG   (NB*32*32*32)   // 131,072
#define N8SEG   (NB*16*16*16)   // 16,384

typedef unsigned int uint;

// workspace offsets (bytes)
#define OFF_SUMS2  ((size_t)0)            // N2SEG*64 bf16 = 134,217,728 (NOT pre-zeroed)
#define OFF_CNT2   ((size_t)134217728)    // N2SEG u32     =   4,194,304 (zeroed)
#define OFF_SUMS0F ((size_t)138412032)    // 256 f32 (pad 1024, zeroed; contiguous w/ cnt2)
#define ZERO_BEG   OFF_CNT2
#define ZERO_END   ((size_t)138413056)
#define OFF_SUMS4  ((size_t)138413056)    // N4SEG*64 bf16 =  16,777,216
#define OFF_MEAN4  ((size_t)155190272)    // N4SEG*64 bf16 =  16,777,216
#define OFF_CNT4   ((size_t)171967488)    // N4SEG u32     =     524,288
#define OFF_SUMS8  ((size_t)172491776)    // N8SEG*64 bf16 =   2,097,152
#define OFF_MEAN8  ((size_t)174588928)    // N8SEG*64 bf16 =   2,097,152
#define OFF_CNT8   ((size_t)176686080)    // N8SEG u32     =      65,536
#define OFF_MEAN0  ((size_t)176751616)    // 4*32 u32 (pad 1024)
#define OFF_WF     ((size_t)176752640)    // 48 KB frag-ready W
#define WS_NEEDED  ((size_t)176801792)

// dword offsets into workspace (for k_final's single-base addressing)
#define D_S2 0u
#define D_C2 ((uint)(OFF_CNT2 / 4))
#define D_M4 ((uint)(OFF_MEAN4 / 4))
#define D_M8 ((uint)(OFF_MEAN8 / 4))
#define D_M0 ((uint)(OFF_MEAN0 / 4))

typedef short s8v __attribute__((ext_vector_type(8)));   // 8 bf16 (4 VGPR)
typedef float f4v __attribute__((ext_vector_type(4)));   // MFMA C/D
typedef uint  u4v __attribute__((ext_vector_type(4)));
typedef float f2v __attribute__((ext_vector_type(2)));

__device__ __forceinline__ uint pack_bf16x2(float a, float b) {
  uint ua = __float_as_uint(a), ub = __float_as_uint(b);
  ua = (ua + 0x7fffu + ((ua >> 16) & 1u)) >> 16;   // RNE
  ub = (ub + 0x7fffu + ((ub >> 16) & 1u)) >> 16;
  return (ub << 16) | ua;
}
__device__ __forceinline__ float bflo(uint u) { return __uint_as_float(u << 16); }
__device__ __forceinline__ float bfhi(uint u) { return __uint_as_float(u & 0xffff0000u); }

__device__ __forceinline__ uint scale_pk(uint u, float rc) {
  return pack_bf16x2(bflo(u) * rc, bfhi(u) * rc);
}

// ---- zero cnt2 + sums0f (contiguous, 4,195,328 B)
#define ZCNT_U4 ((ZERO_END - ZERO_BEG) / 16)
__global__ __launch_bounds__(256) void k_zero_cnt(u4v* __restrict__ p) {
  u4v z = (u4v)0u;
  size_t stride = (size_t)gridDim.x * 256;
  for (size_t i = blockIdx.x * 256ull + threadIdx.x; i < ZCNT_U4; i += stride)
    __builtin_nontemporal_store(z, &p[i]);
}

// ---- phase 1: count points per level-2 voxel (1 thread = 1 point)
__global__ __launch_bounds__(256) void k_cnt(
    const int* __restrict__ coords, const int* __restrict__ batch,
    uint* __restrict__ cnt2)
{
  int p = blockIdx.x * 256 + threadIdx.x;          // grid sized exactly N_PTS
  int b = batch[p];
  int x = coords[3 * p], y = coords[3 * p + 1], z = coords[3 * p + 2];
  int s2 = ((b * 64 + (x >> 1)) * 64 + (y >> 1)) * 64 + (z >> 1);
  atomicAdd(&cnt2[s2], 1u);
}

// ---- phase 1.5: zero only rows that will be atomically accumulated (cnt>=2)
__global__ __launch_bounds__(256) void k_zmulti(
    const uint* __restrict__ cnt2, u4v* __restrict__ sums2q)
{
  int tid = blockIdx.x * 256 + threadIdx.x;        // grid = N2SEG*8 exactly
  int seg = tid >> 3, part = tid & 7;
  if (cnt2[seg] >= 2u) sums2q[seg * 8 + part] = (u4v)0u;
}

// ---- frag-ready W: Wf[((kt*6+nt)*64+l)*4+d] = pack(W[n][k], W[n][k+1])
//      n = nt*16+(l&15), k = kt*32+(l>>4)*8+2d   (B[k][n] = W[n][k])
__global__ __launch_bounds__(256) void k_wf(const float* __restrict__ W,
                                            uint* __restrict__ Wf) {
  int idx = blockIdx.x * 256 + threadIdx.x;        // < 12288
  int d = idx & 3, l = (idx >> 2) & 63, ktnt = idx >> 8;
  int kt = ktnt / 6, nt = ktnt - kt * 6;
  int n = nt * 16 + (l & 15);
  int k = kt * 32 + (l >> 4) * 8 + d * 2;
  Wf[idx] = pack_bf16x2(W[n * 256 + k], W[n * 256 + k + 1]);
}

// ---- phase 2: scatter feats. cnt==1 -> plain store; cnt>=2 -> pk-bf16 atomic
__global__ __launch_bounds__(256) void k_scatter2(
    const float* __restrict__ feats, const int* __restrict__ coords,
    const int* __restrict__ batch, uint* __restrict__ sums2,
    const uint* __restrict__ cnt2)
{
  int l = threadIdx.x & 63;
  int c2 = l & 31, half = l >> 5;
  int wid = (blockIdx.x * 256 + threadIdx.x) >> 6;
  int nw = (gridDim.x * 256) >> 6;
  for (int p0 = wid * 2; p0 < N_PTS; p0 += nw * 2) {
    int p = p0 + half;
    f2v f = __builtin_nontemporal_load(((const f2v*)feats) + (size_t)p * 32 + c2);
    int b = batch[p];
    int x = coords[3 * p], y = coords[3 * p + 1], z = coords[3 * p + 2];
    int s2 = ((b * 64 + (x >> 1)) * 64 + (y >> 1)) * 64 + (z >> 1);
    uint pk = pack_bf16x2(f.x, f.y);
    uint cv = cnt2[s2];                   // same addr across 32 lanes: broadcast
    uint* dst = sums2 + (size_t)s2 * 32 + c2;
    if (cv == 1u) {
      *dst = pk;                          // solo voxel: no RMW needed
    } else {
      uint64_t addr = (uint64_t)(uintptr_t)dst;
      asm volatile("global_atomic_pk_add_bf16 %0, %1, off"
                   :: "v"(addr), "v"(pk));
    }
  }
}

// ---- 8-child tree reduction; cnt-guarded (empty level-2 rows are unwritten
//      poison -> must skip). Writes raw sums, pre-scaled mean, and cnt.
__global__ __launch_bounds__(256) void k_down_bf(
    const uint* __restrict__ sumsF, const uint* __restrict__ cntF,
    uint* __restrict__ sumsC, uint* __restrict__ meanC,
    uint* __restrict__ cntC, int lgC, int nC)
{
  int tid = blockIdx.x * 256 + threadIdx.x;
  int sc = tid >> 5, c2 = tid & 31;
  if (sc >= nC) return;
  int CG = 1 << lgC, FG = CG << 1;
  int b = sc >> (3 * lgC);
  int r = sc & ((1 << (3 * lgC)) - 1);
  int x = r >> (2 * lgC), y = (r >> lgC) & (CG - 1), z = r & (CG - 1);
  float sx = 0.f, sy = 0.f;
  uint cn = 0;
  #pragma unroll
  for (int dx = 0; dx < 2; ++dx)
    #pragma unroll
    for (int dy = 0; dy < 2; ++dy)
      #pragma unroll
      for (int dz = 0; dz < 2; ++dz) {
        int sf = ((b * FG + 2 * x + dx) * FG + (2 * y + dy)) * FG + (2 * z + dz);
        uint cf = cntF[sf];               // same addr across 32 lanes: broadcast
        if (cf) {
          uint u = sumsF[(size_t)sf * 32 + c2];
          sx += bflo(u); sy += bfhi(u);
        }
        cn += cf;
      }
  sumsC[(size_t)sc * 32 + c2] = pack_bf16x2(sx, sy);
  float rc = 1.0f / (float)(cn > 1u ? cn : 1u);
  meanC[(size_t)sc * 32 + c2] = pack_bf16x2(sx * rc, sy * rc);
  if (c2 == 0) cntC[sc] = cn;
}

// ---- per-batch global partial reduce (32 blocks/batch), f32 atomics
__global__ __launch_bounds__(256) void k_gpart(
    const uint* __restrict__ sums8, float* __restrict__ sums0f)
{
  __shared__ float2 red[8][32];
  int b = blockIdx.x >> 5, chunk = blockIdx.x & 31;
  int t = threadIdx.x, c2 = t & 31, g = t >> 5;
  float sx = 0.f, sy = 0.f;
  for (int i = g; i < 128; i += 8) {
    uint u = sums8[(size_t)(b * 4096 + chunk * 128 + i) * 32 + c2];
    sx += bflo(u); sy += bfhi(u);
  }
  red[g][c2] = make_float2(sx, sy);
  __syncthreads();
  if (g == 0) {
    float ax = 0.f, ay = 0.f;
    #pragma unroll
    for (int i = 0; i < 8; ++i) { ax += red[i][c2].x; ay += red[i][c2].y; }
    unsafeAtomicAdd(&sums0f[b * 64 + 2 * c2], ax);
    unsafeAtomicAdd(&sums0f[b * 64 + 2 * c2 + 1], ay);
  }
}

// ---- finalize level 0: cnt0 from cnt8, mean0 = sums0f/cnt0 (bf16, pre-scaled)
__global__ __launch_bounds__(256) void k_fin0(
    const float* __restrict__ sums0f, const uint* __restrict__ cnt8,
    uint* __restrict__ mean0)
{
  __shared__ uint redc[256];
  __shared__ float rcs[NB];
  int t = threadIdx.x;
  uint cn = 0;
  for (int i = 0; i < 64; ++i) cn += cnt8[t * 64 + i];
  redc[t] = cn;
  __syncthreads();
  if (t < NB) {
    uint s = 0;
    for (int i = 0; i < 64; ++i) s += redc[t * 64 + i];
    rcs[t] = 1.0f / (float)(s > 1u ? s : 1u);
  }
  __syncthreads();
  if (t < 128) {
    int b = t >> 5, c2 = t & 31;
    float rc = rcs[b];
    mean0[b * 32 + c2] =
        pack_bf16x2(sums0f[b * 64 + 2 * c2] * rc, sums0f[b * 64 + 2 * c2 + 1] * rc);
  }
}

// ---- fused gather-GEMM, v10: LDS index prologue + depth-3 named-buffer
//      pipeline. 512 points/block, 4 waves, 52KB LDS (3 blocks/CU).
#define GPB 8

#define ISSUE(G, AF, CV) {                                                   \
    uint2 iv = idx_lds[(G) * 64 + w16pl];                                    \
    const uint4* a2 = (const uint4*)(wsb + D_S2 + iv.x * 32u);               \
    const uint4* a4 = (const uint4*)(wsb + D_M4 + (iv.y & 0x1FFFFu) * 32u);  \
    const uint4* a8 = (const uint4*)(wsb + D_M8 + (iv.y >> 17) * 32u);       \
    const uint4* a0 = (const uint4*)(wsb + D_M0 + (iv.y >> 29) * 32u);       \
    AF[0] = a0[q];  AF[1] = a0[4 + q];                                       \
    AF[2] = a2[q];  AF[3] = a2[4 + q];                                       \
    AF[4] = a4[q];  AF[5] = a4[4 + q];                                       \
    AF[6] = a8[q];  AF[7] = a8[4 + q];                                       \
    CV = wsb[D_C2 + iv.x];                                                   \
  }

#define CONSUME(G, AF, CV) {                                                 \
    float rc = 1.0f / (float)(CV > 1u ? CV : 1u);                            \
    AF[2].x = scale_pk(AF[2].x, rc); AF[2].y = scale_pk(AF[2].y, rc);        \
    AF[2].z = scale_pk(AF[2].z, rc); AF[2].w = scale_pk(AF[2].w, rc);        \
    AF[3].x = scale_pk(AF[3].x, rc); AF[3].y = scale_pk(AF[3].y, rc);        \
    AF[3].z = scale_pk(AF[3].z, rc); AF[3].w = scale_pk(AF[3].w, rc);        \
    f4v acc[6];                                                              \
    _Pragma("unroll")                                                        \
    for (int nt = 0; nt < 6; ++nt) acc[nt] = (f4v)0.0f;                      \
    _Pragma("unroll")                                                        \
    for (int kt = 0; kt < 8; ++kt) {                                         \
      s8v afr = __builtin_bit_cast(s8v, AF[kt]);                             \
      _Pragma("unroll")                                                      \
      for (int nt = 0; nt < 6; ++nt) {                                       \
        s8v bf = __builtin_bit_cast(s8v, wf[(kt * 6 + nt) * 64 + l]);        \
        acc[nt] = __builtin_amdgcn_mfma_f32_16x16x32_bf16(afr, bf, acc[nt], 0, 0, 0); \
      }                                                                      \
    }                                                                        \
    float* ob = out + (size_t)(pb + (G) * 64 + w * 16 + q * 4) * 96 + pl;    \
    _Pragma("unroll")                                                        \
    for (int nt = 0; nt < 6; ++nt)                                           \
      _Pragma("unroll")                                                      \
      for (int r = 0; r < 4; ++r)                                            \
        ob[r * 96 + nt * 16] = bn[nt] + acc[nt][r];                          \
  }

__global__ __launch_bounds__(256) void k_final(
    const int* __restrict__ coords, const int* __restrict__ batch,
    const uint* __restrict__ wsb,     // workspace base, dword-indexed
    const uint4* __restrict__ Wf, const float* __restrict__ bias,
    float* __restrict__ out)
{
  __shared__ uint4 wf[3072];     // 48 KB frag-ready W
  __shared__ uint2 idx_lds[512]; // 4 KB packed indices (s2 | s4 + s8<<17)
  int t = threadIdx.x;
  #pragma unroll
  for (int i = 0; i < 12; ++i) wf[i * 256 + t] = Wf[i * 256 + t];
  int pb = blockIdx.x * (GPB * 64);
  #pragma unroll
  for (int j = 0; j < 2; ++j) {
    int pi = t + j * 256;
    int p = pb + pi;
    int b = batch[p];
    int x = coords[3 * p], y = coords[3 * p + 1], z = coords[3 * p + 2];
    uint s2 = (uint)(((b * 64 + (x >> 1)) * 64 + (y >> 1)) * 64 + (z >> 1));
    uint s4 = (uint)(((b * 32 + (x >> 2)) * 32 + (y >> 2)) * 32 + (z >> 2));
    uint s8 = (uint)(((b * 16 + (x >> 3)) * 16 + (y >> 3)) * 16 + (z >> 3));
    idx_lds[pi] = make_uint2(s2, s4 | (s8 << 17));   // b == s8 >> 12 == iv.y >> 29
  }
  int l = t & 63, w = t >> 6, pl = l & 15, q = l >> 4;
  int w16pl = w * 16 + pl;
  float bn[6];
  #pragma unroll
  for (int nt = 0; nt < 6; ++nt) bn[nt] = bias[nt * 16 + pl];
  __syncthreads();

  uint4 b0[8], b1[8], b2[8];
  uint c0, c1, c2v;
  ISSUE(0, b0, c0)
  ISSUE(1, b1, c1)
  ISSUE(2, b2, c2v)  CONSUME(0, b0, c0)
  ISSUE(3, b0, c0)   CONSUME(1, b1, c1)
  ISSUE(4, b1, c1)   CONSUME(2, b2, c2v)
  ISSUE(5, b2, c2v)  CONSUME(3, b0, c0)
  ISSUE(6, b0, c0)   CONSUME(4, b1, c1)
  ISSUE(7, b1, c1)   CONSUME(5, b2, c2v)
  CONSUME(6, b0, c0)
  CONSUME(7, b1, c1)
}

extern "C" void kernel_launch(void* const* d_in, const int* in_sizes, int n_in,
                              void* d_out, int out_size, void* d_ws, size_t ws_size,
                              hipStream_t stream)
{
  const float* feats  = (const float*)d_in[0];
  const int*   coords = (const int*)d_in[1];
  const int*   batch  = (const int*)d_in[2];
  const float* W      = (const float*)d_in[3];
  const float* bias   = (const float*)d_in[4];
  float* out = (float*)d_out;
  char* ws = (char*)d_ws;
  if (ws_size < WS_NEEDED) return;

  uint*  sums2  = (uint*)(ws + OFF_SUMS2);
  uint*  cnt2   = (uint*)(ws + OFF_CNT2);
  float* sums0f = (float*)(ws + OFF_SUMS0F);
  uint*  sums4  = (uint*)(ws + OFF_SUMS4);
  uint*  mean4  = (uint*)(ws + OFF_MEAN4);
  uint*  cnt4   = (uint*)(ws + OFF_CNT4);
  uint*  sums8  = (uint*)(ws + OFF_SUMS8);
  uint*  mean8  = (uint*)(ws + OFF_MEAN8);
  uint*  cnt8   = (uint*)(ws + OFF_CNT8);
  uint*  mean0  = (uint*)(ws + OFF_MEAN0);
  uint*  Wf     = (uint*)(ws + OFF_WF);

  k_wf<<<48, 256, 0, stream>>>(W, Wf);
  k_zero_cnt<<<1024, 256, 0, stream>>>((u4v*)(ws + ZERO_BEG));
  k_cnt<<<N_PTS / 256, 256, 0, stream>>>(coords, batch, cnt2);
  k_zmulti<<<(N2SEG * 8) / 256, 256, 0, stream>>>(cnt2, (u4v*)sums2);
  k_scatter2<<<8192, 256, 0, stream>>>(feats, coords, batch, sums2, cnt2);
  k_down_bf<<<(N4SEG * 32) / 256, 256, 0, stream>>>(sums2, cnt2, sums4, mean4, cnt4, 5, N4SEG);
  k_down_bf<<<(N8SEG * 32) / 256, 256, 0, stream>>>(sums4, cnt4, sums8, mean8, cnt8, 4, N8SEG);
  k_gpart<<<128, 256, 0, stream>>>(sums8, sums0f);
  k_fin0<<<1, 256, 0, stream>>>(sums0f, cnt8, mean0);
  k_final<<<N_PTS / (GPB * 64), 256, 0, stream>>>(
      coords, batch, (const uint*)ws, (const uint4*)Wf, bias, out);
}

// Round 11
// 396.726 us; speedup vs baseline: 1.1007x; 1.0371x over previous
//
#include <hip/hip_runtime.h>
#include <stdint.h>

// ---------------------------------------------------------------------------
// SPP: out[n] = b + W @ [mean0(b) | mean2(s2) | mean4(s4) | mean8(s8)]
// v11: = v10 with level-0 folded into a precomputed per-batch bias0[4][96]
//      (rank-4 term, computed f32 in k_fin0). k_final: 6-frag payload,
//      36KB W-LDS + 2KB s2-idx (s4/s8/b derived from s2 bits) + 1.5KB bias0
//      -> 39.5KB LDS = 4 blocks/CU; depth-3 pipeline kept.
// ---------------------------------------------------------------------------

#define N_PTS   1048576
#define NB      4
#define N2SEG   (NB*64*64*64)   // 1,048,576
#define N4SEG   (NB*32*32*32)   // 131,072
#define N8SEG   (NB*16*16*16)   // 16,384

typedef unsigned int uint;

// workspace offsets (bytes)
#define OFF_SUMS2  ((size_t)0)            // N2SEG*64 bf16 = 134,217,728 (NOT pre-zeroed)
#define OFF_CNT2   ((size_t)134217728)    // N2SEG u32     =   4,194,304 (zeroed)
#define OFF_SUMS0F ((size_t)138412032)    // 256 f32 (pad 1024, zeroed; contiguous w/ cnt2)
#define ZERO_BEG   OFF_CNT2
#define ZERO_END   ((size_t)138413056)
#define OFF_SUMS4  ((size_t)138413056)    // N4SEG*64 bf16 =  16,777,216
#define OFF_MEAN4  ((size_t)155190272)    // N4SEG*64 bf16 =  16,777,216
#define OFF_CNT4   ((size_t)171967488)    // N4SEG u32     =     524,288
#define OFF_SUMS8  ((size_t)172491776)    // N8SEG*64 bf16 =   2,097,152
#define OFF_MEAN8  ((size_t)174588928)    // N8SEG*64 bf16 =   2,097,152
#define OFF_CNT8   ((size_t)176686080)    // N8SEG u32     =      65,536
#define OFF_WF     ((size_t)176752640)    // 48 KB frag-ready W
#define OFF_BIAS0  ((size_t)176801792)    // 4*96 f32 = 1536 (pad 2048)
#define WS_NEEDED  ((size_t)176803840)

// dword offsets into workspace (for k_final's single-base addressing)
#define D_S2 0u
#define D_C2 ((uint)(OFF_CNT2 / 4))
#define D_M4 ((uint)(OFF_MEAN4 / 4))
#define D_M8 ((uint)(OFF_MEAN8 / 4))

typedef short s8v __attribute__((ext_vector_type(8)));   // 8 bf16 (4 VGPR)
typedef float f4v __attribute__((ext_vector_type(4)));   // MFMA C/D
typedef uint  u4v __attribute__((ext_vector_type(4)));
typedef float f2v __attribute__((ext_vector_type(2)));

__device__ __forceinline__ uint pack_bf16x2(float a, float b) {
  uint ua = __float_as_uint(a), ub = __float_as_uint(b);
  ua = (ua + 0x7fffu + ((ua >> 16) & 1u)) >> 16;   // RNE
  ub = (ub + 0x7fffu + ((ub >> 16) & 1u)) >> 16;
  return (ub << 16) | ua;
}
__device__ __forceinline__ float bflo(uint u) { return __uint_as_float(u << 16); }
__device__ __forceinline__ float bfhi(uint u) { return __uint_as_float(u & 0xffff0000u); }

__device__ __forceinline__ uint scale_pk(uint u, float rc) {
  return pack_bf16x2(bflo(u) * rc, bfhi(u) * rc);
}

// ---- zero cnt2 + sums0f (contiguous, 4,195,328 B)
#define ZCNT_U4 ((ZERO_END - ZERO_BEG) / 16)
__global__ __launch_bounds__(256) void k_zero_cnt(u4v* __restrict__ p) {
  u4v z = (u4v)0u;
  size_t stride = (size_t)gridDim.x * 256;
  for (size_t i = blockIdx.x * 256ull + threadIdx.x; i < ZCNT_U4; i += stride)
    __builtin_nontemporal_store(z, &p[i]);
}

// ---- phase 1: count points per level-2 voxel (1 thread = 1 point)
__global__ __launch_bounds__(256) void k_cnt(
    const int* __restrict__ coords, const int* __restrict__ batch,
    uint* __restrict__ cnt2)
{
  int p = blockIdx.x * 256 + threadIdx.x;          // grid sized exactly N_PTS
  int b = batch[p];
  int x = coords[3 * p], y = coords[3 * p + 1], z = coords[3 * p + 2];
  int s2 = ((b * 64 + (x >> 1)) * 64 + (y >> 1)) * 64 + (z >> 1);
  atomicAdd(&cnt2[s2], 1u);
}

// ---- phase 1.5: zero only rows that will be atomically accumulated (cnt>=2)
__global__ __launch_bounds__(256) void k_zmulti(
    const uint* __restrict__ cnt2, u4v* __restrict__ sums2q)
{
  int tid = blockIdx.x * 256 + threadIdx.x;        // grid = N2SEG*8 exactly
  int seg = tid >> 3, part = tid & 7;
  if (cnt2[seg] >= 2u) sums2q[seg * 8 + part] = (u4v)0u;
}

// ---- frag-ready W: Wf[((kt*6+nt)*64+l)*4+d] = pack(W[n][k], W[n][k+1])
//      n = nt*16+(l&15), k = kt*32+(l>>4)*8+2d   (B[k][n] = W[n][k])
__global__ __launch_bounds__(256) void k_wf(const float* __restrict__ W,
                                            uint* __restrict__ Wf) {
  int idx = blockIdx.x * 256 + threadIdx.x;        // < 12288
  int d = idx & 3, l = (idx >> 2) & 63, ktnt = idx >> 8;
  int kt = ktnt / 6, nt = ktnt - kt * 6;
  int n = nt * 16 + (l & 15);
  int k = kt * 32 + (l >> 4) * 8 + d * 2;
  Wf[idx] = pack_bf16x2(W[n * 256 + k], W[n * 256 + k + 1]);
}

// ---- phase 2: scatter feats. cnt==1 -> plain store; cnt>=2 -> pk-bf16 atomic
__global__ __launch_bounds__(256) void k_scatter2(
    const float* __restrict__ feats, const int* __restrict__ coords,
    const int* __restrict__ batch, uint* __restrict__ sums2,
    const uint* __restrict__ cnt2)
{
  int l = threadIdx.x & 63;
  int c2 = l & 31, half = l >> 5;
  int wid = (blockIdx.x * 256 + threadIdx.x) >> 6;
  int nw = (gridDim.x * 256) >> 6;
  for (int p0 = wid * 2; p0 < N_PTS; p0 += nw * 2) {
    int p = p0 + half;
    f2v f = __builtin_nontemporal_load(((const f2v*)feats) + (size_t)p * 32 + c2);
    int b = batch[p];
    int x = coords[3 * p], y = coords[3 * p + 1], z = coords[3 * p + 2];
    int s2 = ((b * 64 + (x >> 1)) * 64 + (y >> 1)) * 64 + (z >> 1);
    uint pk = pack_bf16x2(f.x, f.y);
    uint cv = cnt2[s2];                   // same addr across 32 lanes: broadcast
    uint* dst = sums2 + (size_t)s2 * 32 + c2;
    if (cv == 1u) {
      *dst = pk;                          // solo voxel: no RMW needed
    } else {
      uint64_t addr = (uint64_t)(uintptr_t)dst;
      asm volatile("global_atomic_pk_add_bf16 %0, %1, off"
                   :: "v"(addr), "v"(pk));
    }
  }
}

// ---- 8-child tree reduction; cnt-guarded (empty level-2 rows are unwritten
//      poison -> must skip). Writes raw sums, pre-scaled mean, and cnt.
__global__ __launch_bounds__(256) void k_down_bf(
    const uint* __restrict__ sumsF, const uint* __restrict__ cntF,
    uint* __restrict__ sumsC, uint* __restrict__ meanC,
    uint* __restrict__ cntC, int lgC, int nC)
{
  int tid = blockIdx.x * 256 + threadIdx.x;
  int sc = tid >> 5, c2 = tid & 31;
  if (sc >= nC) return;
  int CG = 1 << lgC, FG = CG << 1;
  int b = sc >> (3 * lgC);
  int r = sc & ((1 << (3 * lgC)) - 1);
  int x = r >> (2 * lgC), y = (r >> lgC) & (CG - 1), z = r & (CG - 1);
  float sx = 0.f, sy = 0.f;
  uint cn = 0;
  #pragma unroll
  for (int dx = 0; dx < 2; ++dx)
    #pragma unroll
    for (int dy = 0; dy < 2; ++dy)
      #pragma unroll
      for (int dz = 0; dz < 2; ++dz) {
        int sf = ((b * FG + 2 * x + dx) * FG + (2 * y + dy)) * FG + (2 * z + dz);
        uint cf = cntF[sf];               // same addr across 32 lanes: broadcast
        if (cf) {
          uint u = sumsF[(size_t)sf * 32 + c2];
          sx += bflo(u); sy += bfhi(u);
        }
        cn += cf;
      }
  sumsC[(size_t)sc * 32 + c2] = pack_bf16x2(sx, sy);
  float rc = 1.0f / (float)(cn > 1u ? cn : 1u);
  meanC[(size_t)sc * 32 + c2] = pack_bf16x2(sx * rc, sy * rc);
  if (c2 == 0) cntC[sc] = cn;
}

// ---- per-batch global partial reduce (32 blocks/batch), f32 atomics
__global__ __launch_bounds__(256) void k_gpart(
    const uint* __restrict__ sums8, float* __restrict__ sums0f)
{
  __shared__ float2 red[8][32];
  int b = blockIdx.x >> 5, chunk = blockIdx.x & 31;
  int t = threadIdx.x, c2 = t & 31, g = t >> 5;
  float sx = 0.f, sy = 0.f;
  for (int i = g; i < 128; i += 8) {
    uint u = sums8[(size_t)(b * 4096 + chunk * 128 + i) * 32 + c2];
    sx += bflo(u); sy += bfhi(u);
  }
  red[g][c2] = make_float2(sx, sy);
  __syncthreads();
  if (g == 0) {
    float ax = 0.f, ay = 0.f;
    #pragma unroll
    for (int i = 0; i < 8; ++i) { ax += red[i][c2].x; ay += red[i][c2].y; }
    unsafeAtomicAdd(&sums0f[b * 64 + 2 * c2], ax);
    unsafeAtomicAdd(&sums0f[b * 64 + 2 * c2 + 1], ay);
  }
}

// ---- finalize level 0: cnt0 from cnt8; bias0[b][o] = bias[o] + W0 @ mean0[b]
//      (f32, rank-4 fold of the global-pool level into the epilogue bias)
__global__ __launch_bounds__(256) void k_fin0(
    const float* __restrict__ sums0f, const uint* __restrict__ cnt8,
    const float* __restrict__ W, const float* __restrict__ bias,
    float* __restrict__ bias0)
{
  __shared__ uint redc[256];
  __shared__ float rcs[NB];
  __shared__ float m0[NB * 64];
  int t = threadIdx.x;
  uint cn = 0;
  for (int i = 0; i < 64; ++i) cn += cnt8[t * 64 + i];
  redc[t] = cn;
  __syncthreads();
  if (t < NB) {
    uint s = 0;
    for (int i = 0; i < 64; ++i) s += redc[t * 64 + i];
    rcs[t] = 1.0f / (float)(s > 1u ? s : 1u);
  }
  __syncthreads();
  if (t < NB * 64) m0[t] = sums0f[t] * rcs[t >> 6];
  __syncthreads();
  for (int i = t; i < NB * 96; i += 256) {
    int b = i / 96, o = i - b * 96;
    float s = bias[o];
    const float* wr = W + (size_t)o * 256;
    #pragma unroll 8
    for (int k = 0; k < 64; ++k) s += wr[k] * m0[b * 64 + k];
    bias0[i] = s;
  }
}

// ---- fused gather-GEMM, v11: 6-frag payload (levels 2/4/8 only), s2-only
//      LDS idx (s4/s8/b derived from s2 bit-fields), bias0 epilogue table.
//      39.5KB LDS -> 4 blocks/CU; depth-3 named-buffer pipeline.
#define GPB 8

#define ISSUE(G, AF, CV) {                                                   \
    uint s2i = idx_lds[(G) * 64 + w16pl];                                    \
    uint bb = s2i >> 18, X = (s2i >> 12) & 63u, Y = (s2i >> 6) & 63u,        \
         Z = s2i & 63u;                                                      \
    uint s4i = ((bb * 32 + (X >> 1)) * 32 + (Y >> 1)) * 32 + (Z >> 1);       \
    uint s8i = ((bb * 16 + (X >> 2)) * 16 + (Y >> 2)) * 16 + (Z >> 2);       \
    const uint4* a2 = (const uint4*)(wsb + D_S2 + s2i * 32u);                \
    const uint4* a4 = (const uint4*)(wsb + D_M4 + s4i * 32u);                \
    const uint4* a8 = (const uint4*)(wsb + D_M8 + s8i * 32u);                \
    AF[0] = a2[q];  AF[1] = a2[4 + q];                                       \
    AF[2] = a4[q];  AF[3] = a4[4 + q];                                       \
    AF[4] = a8[q];  AF[5] = a8[4 + q];                                       \
    CV = wsb[D_C2 + s2i];                                                    \
  }

#define CONSUME(G, AF, CV) {                                                 \
    float rc = 1.0f / (float)(CV > 1u ? CV : 1u);                            \
    AF[0].x = scale_pk(AF[0].x, rc); AF[0].y = scale_pk(AF[0].y, rc);        \
    AF[0].z = scale_pk(AF[0].z, rc); AF[0].w = scale_pk(AF[0].w, rc);        \
    AF[1].x = scale_pk(AF[1].x, rc); AF[1].y = scale_pk(AF[1].y, rc);        \
    AF[1].z = scale_pk(AF[1].z, rc); AF[1].w = scale_pk(AF[1].w, rc);        \
    f4v acc[6];                                                              \
    _Pragma("unroll")                                                        \
    for (int nt = 0; nt < 6; ++nt) acc[nt] = (f4v)0.0f;                      \
    _Pragma("unroll")                                                        \
    for (int kt = 0; kt < 6; ++kt) {                                         \
      s8v afr = __builtin_bit_cast(s8v, AF[kt]);                             \
      _Pragma("unroll")                                                      \
      for (int nt = 0; nt < 6; ++nt) {                                       \
        s8v bf = __builtin_bit_cast(s8v, wf[(kt * 6 + nt) * 64 + l]);        \
        acc[nt] = __builtin_amdgcn_mfma_f32_16x16x32_bf16(afr, bf, acc[nt], 0, 0, 0); \
      }                                                                      \
    }                                                                        \
    int base = (G) * 64 + w * 16 + q * 4;                                    \
    float* ob = out + (size_t)(pb + base) * 96 + pl;                         \
    _Pragma("unroll")                                                        \
    for (int r = 0; r < 4; ++r) {                                            \
      uint br = idx_lds[base + r] >> 18;                                     \
      const float* bp = &bias0_l[br * 96 + pl];                              \
      _Pragma("unroll")                                                      \
      for (int nt = 0; nt < 6; ++nt)                                         \
        ob[r * 96 + nt * 16] = bp[nt * 16] + acc[nt][r];                     \
    }                                                                        \
  }

__global__ __launch_bounds__(256) void k_final(
    const int* __restrict__ coords, const int* __restrict__ batch,
    const uint* __restrict__ wsb,     // workspace base, dword-indexed
    const uint4* __restrict__ Wf, const float* __restrict__ bias0,
    float* __restrict__ out)
{
  __shared__ uint4 wf[2304];      // 36 KB: W tiles for kt=2..7 (levels 2/4/8)
  __shared__ uint idx_lds[512];   // 2 KB: s2 per point (s4/s8/b derived)
  __shared__ float bias0_l[NB * 96];  // 1.5 KB
  int t = threadIdx.x;
  #pragma unroll
  for (int i = 0; i < 9; ++i) wf[i * 256 + t] = Wf[768 + i * 256 + t];
  #pragma unroll
  for (int j = 0; j < 2; ++j) {
    int i = t + j * 256;
    if (i < NB * 96) bias0_l[i] = bias0[i];
  }
  int pb = blockIdx.x * (GPB * 64);
  #pragma unroll
  for (int j = 0; j < 2; ++j) {
    int pi = t + j * 256;
    int p = pb + pi;
    int b = batch[p];
    int x = coords[3 * p], y = coords[3 * p + 1], z = coords[3 * p + 2];
    idx_lds[pi] = (uint)(((b * 64 + (x >> 1)) * 64 + (y >> 1)) * 64 + (z >> 1));
  }
  int l = t & 63, w = t >> 6, pl = l & 15, q = l >> 4;
  int w16pl = w * 16 + pl;
  __syncthreads();

  uint4 b0[6], b1[6], b2[6];
  uint c0, c1, c2v;
  ISSUE(0, b0, c0)
  ISSUE(1, b1, c1)
  ISSUE(2, b2, c2v)  CONSUME(0, b0, c0)
  ISSUE(3, b0, c0)   CONSUME(1, b1, c1)
  ISSUE(4, b1, c1)   CONSUME(2, b2, c2v)
  ISSUE(5, b2, c2v)  CONSUME(3, b0, c0)
  ISSUE(6, b0, c0)   CONSUME(4, b1, c1)
  ISSUE(7, b1, c1)   CONSUME(5, b2, c2v)
  CONSUME(6, b0, c0)
  CONSUME(7, b1, c1)
}

extern "C" void kernel_launch(void* const* d_in, const int* in_sizes, int n_in,
                              void* d_out, int out_size, void* d_ws, size_t ws_size,
                              hipStream_t stream)
{
  const float* feats  = (const float*)d_in[0];
  const int*   coords = (const int*)d_in[1];
  const int*   batch  = (const int*)d_in[2];
  const float* W      = (const float*)d_in[3];
  const float* bias   = (const float*)d_in[4];
  float* out = (float*)d_out;
  char* ws = (char*)d_ws;
  if (ws_size < WS_NEEDED) return;

  uint*  sums2  = (uint*)(ws + OFF_SUMS2);
  uint*  cnt2   = (uint*)(ws + OFF_CNT2);
  float* sums0f = (float*)(ws + OFF_SUMS0F);
  uint*  sums4  = (uint*)(ws + OFF_SUMS4);
  uint*  mean4  = (uint*)(ws + OFF_MEAN4);
  uint*  cnt4   = (uint*)(ws + OFF_CNT4);
  uint*  sums8  = (uint*)(ws + OFF_SUMS8);
  uint*  mean8  = (uint*)(ws + OFF_MEAN8);
  uint*  cnt8   = (uint*)(ws + OFF_CNT8);
  uint*  Wf     = (uint*)(ws + OFF_WF);
  float* bias0  = (float*)(ws + OFF_BIAS0);

  k_wf<<<48, 256, 0, stream>>>(W, Wf);
  k_zero_cnt<<<1024, 256, 0, stream>>>((u4v*)(ws + ZERO_BEG));
  k_cnt<<<N_PTS / 256, 256, 0, stream>>>(coords, batch, cnt2);
  k_zmulti<<<(N2SEG * 8) / 256, 256, 0, stream>>>(cnt2, (u4v*)sums2);
  k_scatter2<<<8192, 256, 0, stream>>>(feats, coords, batch, sums2, cnt2);
  k_down_bf<<<(N4SEG * 32) / 256, 256, 0, stream>>>(sums2, cnt2, sums4, mean4, cnt4, 5, N4SEG);
  k_down_bf<<<(N8SEG * 32) / 256, 256, 0, stream>>>(sums4, cnt4, sums8, mean8, cnt8, 4, N8SEG);
  k_gpart<<<128, 256, 0, stream>>>(sums8, sums0f);
  k_fin0<<<1, 256, 0, stream>>>(sums0f, cnt8, W, bias, bias0);
  k_final<<<N_PTS / (GPB * 64), 256, 0, stream>>>(
      coords, batch, (const uint*)ws, (const uint4*)Wf, bias0, out);
}